// Round 4
// baseline (127.757 us; speedup 1.0000x reference)
//
#include <hip/hip_runtime.h>
#include <math.h>

#define BB 16
#define TD 1024
#define HD 512
#define UD 600
#define AD 80
#define KG 10
#define PC 30      // 3*K
#define PP 32      // padded param cols

#define LOG2E 1.4426950408889634f

#if __has_builtin(__builtin_amdgcn_exp2f)
#define EXP2F(x) __builtin_amdgcn_exp2f(x)
#else
#define EXP2F(x) exp2f(x)
#endif

// ======== kernel 1: params GEMM + exp + transform ========
// [16384 x 512] @ [512 x 30]. 512 blocks x 256 thr; thread = (rp 0..15, s 0..15):
// 2 rows (blk*32 + 2rp, +1), h-slice [32s, 32s+32). Full W staged once into a
// 64 KB LDS image, cols padded to 32, 16B granules XOR-swizzled by (s&7) so the
// 4 distinct slices inside a wave hit disjoint banks (16-way broadcast, 0 conflict).
// 8 b128 LDS reads feed 60 FMAs (2-row reuse): per-CU LDS issue = 8 waves x 256
// b128 x 12cyc = 10.2 us bound. Cross-slice reduce via LDS (s-stride 1000).
// ep[row][32]: c 0..9 a=exp(p); 10..19 nb=-exp(p)*log2e; 20..29 k=exp(p)
#define RPB 32     // rows per block

__global__ __launch_bounds__(256) void k_params(const float* __restrict__ x,
                                                const float* __restrict__ W,
                                                const float* __restrict__ bias,
                                                float* __restrict__ ep) {
    __shared__ float lw[512 * 32];   // 64 KB exactly; reused as reduction buffer

    int tid = threadIdx.x;

    // ---- stage full W, padded + swizzled: phys granule = (c>>2) ^ ((h>>5)&7)
    for (int idx = tid; idx < 512 * 32; idx += 256) {
        int h = idx >> 5, c = idx & 31;
        float v = (c < PC) ? W[h * PC + c] : 0.f;
        int sx_ = (h >> 5) & 7;
        lw[(h << 5) + ((((c >> 2) ^ sx_)) << 2) + (c & 3)] = v;
    }
    __syncthreads();

    int rp = tid & 15;        // row-pair id
    int s  = tid >> 4;        // h-slice 0..15
    int sx = s & 7;
    long row0 = (long)blockIdx.x * RPB + rp * 2;
    const float* xr0 = x + row0 * HD + s * 32;
    const float* xr1 = xr0 + HD;

    float acc0[PC], acc1[PC];
    #pragma unroll
    for (int c = 0; c < PC; c++) { acc0[c] = 0.f; acc1[c] = 0.f; }

    const float* wbase = &lw[(s * 32) << 5];   // h = s*32 + hb
    #pragma unroll 2
    for (int hb = 0; hb < 32; hb += 4) {
        float4 xa = *(const float4*)(xr0 + hb);
        float4 xb = *(const float4*)(xr1 + hb);
        #pragma unroll
        for (int j = 0; j < 4; j++) {
            const float* wr = wbase + ((hb + j) << 5);
            float w[32];
            #pragma unroll
            for (int g = 0; g < 8; g++)
                *(float4*)&w[g * 4] = *(const float4*)&wr[(g ^ sx) << 2];
            float xs0 = (j == 0) ? xa.x : (j == 1) ? xa.y : (j == 2) ? xa.z : xa.w;
            float xs1 = (j == 0) ? xb.x : (j == 1) ? xb.y : (j == 2) ? xb.z : xb.w;
            #pragma unroll
            for (int c = 0; c < PC; c++) {
                acc0[c] += xs0 * w[c];
                acc1[c] += xs1 * w[c];
            }
        }
    }

    __syncthreads();   // all FMA reads of lw done; reuse as reduction buffer
    // red[s][r][c] at s*1000 + r*31 + c  (1000%32=8 -> s shifts banks; <=2-way)
    #pragma unroll
    for (int c = 0; c < PC; c++) {
        lw[s * 1000 + (rp * 2) * 31 + c]     = acc0[c];
        lw[s * 1000 + (rp * 2 + 1) * 31 + c] = acc1[c];
    }
    __syncthreads();

    for (int idx = tid; idx < RPB * PC; idx += 256) {
        int r = idx / PC, c = idx - r * PC;
        float v = 0.f;
        #pragma unroll
        for (int s2 = 0; s2 < 16; s2++)
            v += lw[s2 * 1000 + r * 31 + c];
        float e = __expf(v + bias[c]);
        float val = (c >= 10 && c < 20) ? (-e * LOG2E) : e;
        ep[((long)blockIdx.x * RPB + r) * PP + c] = val;
    }
}

// ======== kernel 2: fused gaussian window + btu,bua->bta einsum ========
// Dynamic u-range: per-block bound from actual a,b,k skips chunks whose every
// term < 2^-46 * max(a,1) -> absolute error < 1e-9 for any input; graceful
// fallback to the full u loop for adversarial params.
#define TT 32     // t-tile per block
#define UC 40     // u chunk
#define NCHUNK 15 // 600/40
#define NTHR 320  // 5 waves

__global__ __launch_bounds__(NTHR) void k_main(const float* __restrict__ ep,
                                               const float* __restrict__ cs,
                                               float* __restrict__ out) {
    __shared__ float params_l[TT * 36];   // pitch 36: float4-aligned rows
    __shared__ float cs_l[UC * AD];       // [u][a] pitch 80
    __shared__ float phi2[TT * 44];       // [t][u] pitch 44: b128 write+read
    __shared__ float range_l[2];

    int tid = threadIdx.x;
    int b = blockIdx.y;
    int t0 = blockIdx.x * TT;
    long r0 = (long)b * TD + t0;

    // ---- stage params: 1024 floats = 256 float4
    if (tid < 256) {
        float4 v = *(const float4*)(ep + r0 * PP + tid * 4);
        int tt_ = tid >> 3, j = (tid & 7) * 4;
        *(float4*)&params_l[tt_ * 36 + j] = v;
    }
    __syncthreads();

    // ---- phi role: thread owns t = tt (tid&31), u-slice sub (tid>>5, 0..9)
    int tt = tid & 31;
    int sub = tid >> 5;
    float pa[KG], pnb[KG], pk[KG];
    #pragma unroll
    for (int q = 0; q < KG; q++) {
        pa[q]  = params_l[tt * 36 + q];
        pnb[q] = params_l[tt * 36 + 10 + q];
        pk[q]  = params_l[tt * 36 + 20 + q];
    }

    // ---- dynamic contributing u-range; wave 0 reduces (covers all 32 t's)
    {
        float lo = 1e30f, hi = -1e30f;
        #pragma unroll
        for (int q = 0; q < KG; q++) {
            float bits = 46.f + fmaxf(0.f, __log2f(pa[q]));
            float w = __fsqrt_rn(bits / (-pnb[q]));   // pnb<0 strictly
            lo = fminf(lo, pk[q] - w);
            hi = fmaxf(hi, pk[q] + w);
        }
        if (tid < 64) {
            #pragma unroll
            for (int m = 1; m < 64; m <<= 1) {
                lo = fminf(lo, __shfl_xor(lo, m));
                hi = fmaxf(hi, __shfl_xor(hi, m));
            }
            if (tid == 0) { range_l[0] = lo; range_l[1] = hi; }
        }
    }
    __syncthreads();
    float lo_m = fminf(fmaxf(range_l[0], 0.f), (float)(UD - 1));
    float hi_m = fminf(fmaxf(range_l[1], 0.f), (float)(UD - 1));
    int ch_lo = (int)lo_m / UC;
    int ch_hi = (int)hi_m / UC;
    if (ch_lo > ch_hi) ch_lo = ch_hi;

    // ---- einsum role: thread owns t-pair ty*2, a-quad tx*4
    int tx = tid % 20;   // 0..19
    int ty = tid / 20;   // 0..15
    float4 acc0 = {0.f, 0.f, 0.f, 0.f};
    float4 acc1 = {0.f, 0.f, 0.f, 0.f};

    const float* csb = cs + (long)b * UD * AD;

    for (int ch = ch_lo; ch <= ch_hi; ch++) {
        int u0 = ch * UC;
        __syncthreads();   // protect cs_l/phi2 from previous einsum readers

        // stage char_seq chunk: 3200 floats = 800 float4, coalesced
        for (int idx = tid; idx < (UC * AD) / 4; idx += NTHR) {
            *(float4*)&cs_l[idx * 4] = *(const float4*)&csb[u0 * AD + idx * 4];
        }

        // compute phi for my t, my 4 u's; one b128 LDS write
        float ph[4];
        #pragma unroll
        for (int i = 0; i < 4; i++) {
            float uf = (float)(u0 + sub * 4 + i);
            float ss = 0.f;
            #pragma unroll
            for (int q = 0; q < KG; q++) {
                float d = uf - pk[q];
                ss += pa[q] * EXP2F(pnb[q] * d * d);
            }
            ph[i] = ss;
        }
        *(float4*)&phi2[tt * 44 + sub * 4] = make_float4(ph[0], ph[1], ph[2], ph[3]);
        __syncthreads();

        // einsum: out[t][a] += phi[t][u] * cs[u][a]; b128 phi + b128 cs
        #pragma unroll 2
        for (int g = 0; g < 10; g++) {
            float4 p0 = *(const float4*)&phi2[(ty * 2) * 44 + g * 4];
            float4 p1 = *(const float4*)&phi2[(ty * 2 + 1) * 44 + g * 4];
            #pragma unroll
            for (int i = 0; i < 4; i++) {
                float4 c4 = *(const float4*)&cs_l[(g * 4 + i) * AD + tx * 4];
                float pi0 = (i == 0) ? p0.x : (i == 1) ? p0.y : (i == 2) ? p0.z : p0.w;
                float pi1 = (i == 0) ? p1.x : (i == 1) ? p1.y : (i == 2) ? p1.z : p1.w;
                acc0.x += pi0 * c4.x; acc0.y += pi0 * c4.y;
                acc0.z += pi0 * c4.z; acc0.w += pi0 * c4.w;
                acc1.x += pi1 * c4.x; acc1.y += pi1 * c4.y;
                acc1.z += pi1 * c4.z; acc1.w += pi1 * c4.w;
            }
        }
    }

    // ---- store 2 t-rows x 4 a's
    long t = r0 + ty * 2;
    *(float4*)(out + t * AD + tx * 4) = acc0;
    *(float4*)(out + (t + 1) * AD + tx * 4) = acc1;
}

extern "C" void kernel_launch(void* const* d_in, const int* in_sizes, int n_in,
                              void* d_out, int out_size, void* d_ws, size_t ws_size,
                              hipStream_t stream) {
    const float* lstm = (const float*)d_in[0];   // [16,1024,512]
    const float* cs   = (const float*)d_in[1];   // [16,600,80]
    const float* W    = (const float*)d_in[2];   // [512,30]
    const float* bias = (const float*)d_in[3];   // [30]
    float* out = (float*)d_out;                  // [16,1024,80]

    float* ep = (float*)d_ws;                    // 16384*32 floats = 2 MB

    k_params<<<(BB * TD) / RPB, 256, 0, stream>>>(lstm, W, bias, ep);
    dim3 grid(TD / TT, BB);
    k_main<<<grid, NTHR, 0, stream>>>(ep, cs, out);
}

// Round 5
// 98.266 us; speedup vs baseline: 1.3001x; 1.3001x over previous
//
#include <hip/hip_runtime.h>
#include <math.h>

#define BB 16
#define TD 1024
#define HD 512
#define UD 600
#define AD 80
#define KG 10
#define PC 30      // 3*K
#define PP 32      // padded param cols

#define LOG2E 1.4426950408889634f

#if __has_builtin(__builtin_amdgcn_exp2f)
#define EXP2F(x) __builtin_amdgcn_exp2f(x)
#else
#define EXP2F(x) exp2f(x)
#endif

// ======== kernel 1: params GEMM + exp + transform ========
// [16384 x 512] @ [512 x 30]. 256 blocks x 1024 thr (16 waves).
// Block = 64 rows (one per lane); wave w owns h-slice [32w, 32w+32).
// W offsets are wave-uniform (readfirstlane) + compile-time -> s_load batches:
// W costs zero vector issue, FMA second operand comes from SGPRs.
// All 8 x-float4 loads issued up-front for VMEM ILP (latency-bound fix:
// R1-R3 all showed VALUBusy<=10%; this kernel was never issue-bound).
// Reduce 16 slices: 16->8 LDS fold (pitch 31, conflict-free) + 8-way sum.
// ep[row][32]: c 0..9 a=exp(p); 10..19 nb=-exp(p)*log2e; 20..29 k=exp(p)
#define KP_ROWS 64

__global__ __launch_bounds__(1024) void k_params(const float* __restrict__ x,
                                                 const float* __restrict__ W,
                                                 const float* __restrict__ bias,
                                                 float* __restrict__ ep) {
    __shared__ float red[8 * KP_ROWS * 31];   // 63488 B

    int tid = threadIdx.x;
    int wv = __builtin_amdgcn_readfirstlane(tid >> 6);   // 0..15, SGPR
    int lane = tid & 63;                                 // row within block
    long row = (long)blockIdx.x * KP_ROWS + lane;

    const float* xr = x + row * HD + wv * 32;
    const float* wr = W + (long)wv * 32 * PC;            // wave-uniform base

    // issue all 8 x loads up-front (8 outstanding VMEM per wave)
    float4 xv[8];
    #pragma unroll
    for (int i = 0; i < 8; i++) xv[i] = *(const float4*)(xr + i * 4);

    float acc[PC];
    #pragma unroll
    for (int c = 0; c < PC; c++) acc[c] = 0.f;

    #pragma unroll
    for (int i = 0; i < 8; i++) {
        #pragma unroll
        for (int j = 0; j < 4; j++) {
            float xs = (j == 0) ? xv[i].x : (j == 1) ? xv[i].y
                     : (j == 2) ? xv[i].z : xv[i].w;
            #pragma unroll
            for (int c = 0; c < PC; c++)
                acc[c] += xs * wr[(i * 4 + j) * PC + c];  // const offset -> s_load
        }
    }

    // ---- fold 16 partial slices -> 8 (wave-uniform branches)
    if (wv >= 8) {
        #pragma unroll
        for (int c = 0; c < PC; c++)
            red[(wv - 8) * (KP_ROWS * 31) + lane * 31 + c] = acc[c];
    }
    __syncthreads();
    if (wv < 8) {
        #pragma unroll
        for (int c = 0; c < PC; c++)
            red[wv * (KP_ROWS * 31) + lane * 31 + c] += acc[c];
    }
    __syncthreads();

    // ---- final 8-way sum + exp transform: 64 rows x 30 c = 1920 outputs
    for (int idx = tid; idx < KP_ROWS * PC; idx += 1024) {
        int r = idx / PC, c = idx - r * PC;
        float v = 0.f;
        #pragma unroll
        for (int s = 0; s < 8; s++)
            v += red[s * (KP_ROWS * 31) + r * 31 + c];
        float e = __expf(v + bias[c]);
        float val = (c >= 10 && c < 20) ? (-e * LOG2E) : e;
        ep[((long)blockIdx.x * KP_ROWS + r) * PP + c] = val;
    }
}

// ======== kernel 2: fused gaussian window + btu,bua->bta einsum ========
// Dynamic u-range: per-block bound from actual a,b,k skips chunks whose every
// term < 2^-46 * max(a,1) -> absolute error < 1e-9 for any input; graceful
// fallback to the full u loop for adversarial params.
#define TT 32     // t-tile per block
#define UC 40     // u chunk
#define NCHUNK 15 // 600/40
#define NTHR 320  // 5 waves

__global__ __launch_bounds__(NTHR) void k_main(const float* __restrict__ ep,
                                               const float* __restrict__ cs,
                                               float* __restrict__ out) {
    __shared__ float params_l[TT * 36];   // pitch 36: float4-aligned rows
    __shared__ float cs_l[UC * AD];       // [u][a] pitch 80
    __shared__ float phi2[TT * 44];       // [t][u] pitch 44: b128 write+read
    __shared__ float range_l[2];

    int tid = threadIdx.x;
    int b = blockIdx.y;
    int t0 = blockIdx.x * TT;
    long r0 = (long)b * TD + t0;

    // ---- stage params: 1024 floats = 256 float4
    if (tid < 256) {
        float4 v = *(const float4*)(ep + r0 * PP + tid * 4);
        int tt_ = tid >> 3, j = (tid & 7) * 4;
        *(float4*)&params_l[tt_ * 36 + j] = v;
    }
    __syncthreads();

    // ---- phi role: thread owns t = tt (tid&31), u-slice sub (tid>>5, 0..9)
    int tt = tid & 31;
    int sub = tid >> 5;
    float pa[KG], pnb[KG], pk[KG];
    #pragma unroll
    for (int q = 0; q < KG; q++) {
        pa[q]  = params_l[tt * 36 + q];
        pnb[q] = params_l[tt * 36 + 10 + q];
        pk[q]  = params_l[tt * 36 + 20 + q];
    }

    // ---- dynamic contributing u-range; wave 0 reduces (covers all 32 t's)
    {
        float lo = 1e30f, hi = -1e30f;
        #pragma unroll
        for (int q = 0; q < KG; q++) {
            float bits = 46.f + fmaxf(0.f, __log2f(pa[q]));
            float w = __fsqrt_rn(bits / (-pnb[q]));   // pnb<0 strictly
            lo = fminf(lo, pk[q] - w);
            hi = fmaxf(hi, pk[q] + w);
        }
        if (tid < 64) {
            #pragma unroll
            for (int m = 1; m < 64; m <<= 1) {
                lo = fminf(lo, __shfl_xor(lo, m));
                hi = fmaxf(hi, __shfl_xor(hi, m));
            }
            if (tid == 0) { range_l[0] = lo; range_l[1] = hi; }
        }
    }
    __syncthreads();
    float lo_m = fminf(fmaxf(range_l[0], 0.f), (float)(UD - 1));
    float hi_m = fminf(fmaxf(range_l[1], 0.f), (float)(UD - 1));
    int ch_lo = (int)lo_m / UC;
    int ch_hi = (int)hi_m / UC;
    if (ch_lo > ch_hi) ch_lo = ch_hi;

    // ---- einsum role: thread owns t-pair ty*2, a-quad tx*4
    int tx = tid % 20;   // 0..19
    int ty = tid / 20;   // 0..15
    float4 acc0 = {0.f, 0.f, 0.f, 0.f};
    float4 acc1 = {0.f, 0.f, 0.f, 0.f};

    const float* csb = cs + (long)b * UD * AD;

    for (int ch = ch_lo; ch <= ch_hi; ch++) {
        int u0 = ch * UC;
        __syncthreads();   // protect cs_l/phi2 from previous einsum readers

        // stage char_seq chunk: 3200 floats = 800 float4, coalesced
        for (int idx = tid; idx < (UC * AD) / 4; idx += NTHR) {
            *(float4*)&cs_l[idx * 4] = *(const float4*)&csb[u0 * AD + idx * 4];
        }

        // compute phi for my t, my 4 u's; one b128 LDS write
        float ph[4];
        #pragma unroll
        for (int i = 0; i < 4; i++) {
            float uf = (float)(u0 + sub * 4 + i);
            float ss = 0.f;
            #pragma unroll
            for (int q = 0; q < KG; q++) {
                float d = uf - pk[q];
                ss += pa[q] * EXP2F(pnb[q] * d * d);
            }
            ph[i] = ss;
        }
        *(float4*)&phi2[tt * 44 + sub * 4] = make_float4(ph[0], ph[1], ph[2], ph[3]);
        __syncthreads();

        // einsum: out[t][a] += phi[t][u] * cs[u][a]; b128 phi + b128 cs
        #pragma unroll 2
        for (int g = 0; g < 10; g++) {
            float4 p0 = *(const float4*)&phi2[(ty * 2) * 44 + g * 4];
            float4 p1 = *(const float4*)&phi2[(ty * 2 + 1) * 44 + g * 4];
            #pragma unroll
            for (int i = 0; i < 4; i++) {
                float4 c4 = *(const float4*)&cs_l[(g * 4 + i) * AD + tx * 4];
                float pi0 = (i == 0) ? p0.x : (i == 1) ? p0.y : (i == 2) ? p0.z : p0.w;
                float pi1 = (i == 0) ? p1.x : (i == 1) ? p1.y : (i == 2) ? p1.z : p1.w;
                acc0.x += pi0 * c4.x; acc0.y += pi0 * c4.y;
                acc0.z += pi0 * c4.z; acc0.w += pi0 * c4.w;
                acc1.x += pi1 * c4.x; acc1.y += pi1 * c4.y;
                acc1.z += pi1 * c4.z; acc1.w += pi1 * c4.w;
            }
        }
    }

    // ---- store 2 t-rows x 4 a's
    long t = r0 + ty * 2;
    *(float4*)(out + t * AD + tx * 4) = acc0;
    *(float4*)(out + (t + 1) * AD + tx * 4) = acc1;
}

extern "C" void kernel_launch(void* const* d_in, const int* in_sizes, int n_in,
                              void* d_out, int out_size, void* d_ws, size_t ws_size,
                              hipStream_t stream) {
    const float* lstm = (const float*)d_in[0];   // [16,1024,512]
    const float* cs   = (const float*)d_in[1];   // [16,600,80]
    const float* W    = (const float*)d_in[2];   // [512,30]
    const float* bias = (const float*)d_in[3];   // [30]
    float* out = (float*)d_out;                  // [16,1024,80]

    float* ep = (float*)d_ws;                    // 16384*32 floats = 2 MB

    k_params<<<(BB * TD) / KP_ROWS, 1024, 0, stream>>>(lstm, W, bias, ep);
    dim3 grid(TD / TT, BB);
    k_main<<<grid, NTHR, 0, stream>>>(ep, cs, out);
}

// Round 6
// 92.996 us; speedup vs baseline: 1.3738x; 1.0567x over previous
//
#include <hip/hip_runtime.h>
#include <math.h>

#define BB 16
#define TD 1024
#define HD 512
#define UD 600
#define AD 80
#define KG 10
#define PC 30      // 3*K
#define PP 32      // padded param cols

#define LOG2E 1.4426950408889634f

#if __has_builtin(__builtin_amdgcn_exp2f)
#define EXP2F(x) __builtin_amdgcn_exp2f(x)
#else
#define EXP2F(x) exp2f(x)
#endif

typedef short v8s __attribute__((ext_vector_type(8)));
typedef float v4f __attribute__((ext_vector_type(4)));

__device__ inline unsigned short f2bf(float f) {            // RNE fp32->bf16
    unsigned u = __float_as_uint(f);
    return (unsigned short)((u + 0x7FFF + ((u >> 16) & 1)) >> 16);
}

// ======== kernel 0: pack W into MFMA B-fragment order, split bf16 hi/lo ====
// mfma_f32_16x16x32_bf16 B-layout: B[k = (lane>>4)*8 + j][n = lane&15].
// Wf[((kt*2+n)*64 + lane)*8 + j] covers k = kt*32 + (lane>>4)*8 + j,
// c = n*16 + (lane&15)  (c>=30 zero-padded). 32768 entries each for hi/lo.
__global__ void k_wprep(const float* __restrict__ W,
                        unsigned short* __restrict__ Wfh,
                        unsigned short* __restrict__ Wfl) {
    int p = blockIdx.x * 256 + threadIdx.x;
    for (; p < 32768; p += 256 * 32) {
        int j = p & 7, l = (p >> 3) & 63, n = (p >> 9) & 1, kt = p >> 10;
        int k = kt * 32 + ((l >> 4) * 8) + j;
        int c = n * 16 + (l & 15);
        float v = (c < PC) ? W[k * PC + c] : 0.f;
        unsigned short h = f2bf(v);
        float hi_f = __uint_as_float(((unsigned)h) << 16);
        Wfh[p] = h;
        Wfl[p] = f2bf(v - hi_f);
    }
}

// ======== kernel 1: params GEMM via MFMA (split-bf16) + exp transform ======
// [16384 x 512] @ [512 x 32pad]. 1024 blocks x 256 thr (4 waves).
// Block = 16-row tile; wave wv owns k in [128wv, 128wv+128) = 4 ktiles.
// A (x) from global: lane (quad=l>>4, m=l&15) reads x[row0+m][k0+quad*8..+7],
// split hi/lo bf16 in VALU. B frags preloaded by k_wprep (global, L2-hot,
// lane-contiguous b128). 3 MFMA passes (hh, lh, hl) ~= fp32 accuracy.
// 4 wave-partials reduced in LDS. Rationale: every VALU variant (R1-R5)
// was operand-fetch-bound at 23-57us; MFMA amortizes operands 8-per-b128.
// ep[row][32]: c 0..9 a=exp(p); 10..19 nb=-exp(p)*log2e; 20..29 k=exp(p)
__global__ __launch_bounds__(256) void k_params(const float* __restrict__ x,
                                                const unsigned short* __restrict__ Wfh,
                                                const unsigned short* __restrict__ Wfl,
                                                const float* __restrict__ bias,
                                                float* __restrict__ ep) {
    __shared__ float red[4 * 16 * 33];   // [wv][m][c] 8448 B

    int tid = threadIdx.x;
    int wv = tid >> 6;
    int l = tid & 63;
    int quad = l >> 4, m = l & 15;
    long row0 = (long)blockIdx.x * 16;

    const float* xr = x + (row0 + m) * HD + wv * 128 + quad * 8;

    v4f acc[2] = {{0.f, 0.f, 0.f, 0.f}, {0.f, 0.f, 0.f, 0.f}};

    #pragma unroll
    for (int kt = 0; kt < 4; kt++) {
        float4 xa = *(const float4*)(xr + kt * 32);
        float4 xb = *(const float4*)(xr + kt * 32 + 4);
        float xf[8] = {xa.x, xa.y, xa.z, xa.w, xb.x, xb.y, xb.z, xb.w};
        v8s ah, al;
        #pragma unroll
        for (int j = 0; j < 8; j++) {
            unsigned short h = f2bf(xf[j]);
            ah[j] = (short)h;
            al[j] = (short)f2bf(xf[j] - __uint_as_float(((unsigned)h) << 16));
        }
        int ktg = wv * 4 + kt;
        #pragma unroll
        for (int n = 0; n < 2; n++) {
            uint4 uh = *(const uint4*)&Wfh[((ktg * 2 + n) * 64 + l) * 8];
            uint4 ul = *(const uint4*)&Wfl[((ktg * 2 + n) * 64 + l) * 8];
            v8s bh, bl;
            __builtin_memcpy(&bh, &uh, 16);
            __builtin_memcpy(&bl, &ul, 16);
            acc[n] = __builtin_amdgcn_mfma_f32_16x16x32_bf16(ah, bh, acc[n], 0, 0, 0);
            acc[n] = __builtin_amdgcn_mfma_f32_16x16x32_bf16(al, bh, acc[n], 0, 0, 0);
            acc[n] = __builtin_amdgcn_mfma_f32_16x16x32_bf16(ah, bl, acc[n], 0, 0, 0);
        }
    }

    // C/D layout: Drow = quad*4 + reg, Dcol = lane&15 (m89-verified)
    #pragma unroll
    for (int n = 0; n < 2; n++)
        #pragma unroll
        for (int r = 0; r < 4; r++)
            red[wv * 528 + (quad * 4 + r) * 33 + n * 16 + m] = acc[n][r];
    __syncthreads();

    for (int idx = tid; idx < 16 * PP; idx += 256) {
        int mm = idx >> 5, c = idx & 31;
        float val = 0.f;
        if (c < PC) {
            float s = red[0 * 528 + mm * 33 + c] + red[1 * 528 + mm * 33 + c]
                    + red[2 * 528 + mm * 33 + c] + red[3 * 528 + mm * 33 + c];
            float e = __expf(s + bias[c]);
            val = (c >= 10 && c < 20) ? (-e * LOG2E) : e;
        }
        ep[(row0 + mm) * PP + c] = val;
    }
}

// ======== kernel 2: fused gaussian window + btu,bua->bta einsum ========
// Dynamic u-range: per-block bound from actual a,b,k skips chunks whose every
// term < 2^-46 * max(a,1) -> absolute error < 1e-9 for any input; graceful
// fallback to the full u loop for adversarial params.
#define TT 32     // t-tile per block
#define UC 40     // u chunk
#define NCHUNK 15 // 600/40
#define NTHR 320  // 5 waves

__global__ __launch_bounds__(NTHR) void k_main(const float* __restrict__ ep,
                                               const float* __restrict__ cs,
                                               float* __restrict__ out) {
    __shared__ float params_l[TT * 36];   // pitch 36: float4-aligned rows
    __shared__ float cs_l[UC * AD];       // [u][a] pitch 80
    __shared__ float phi2[TT * 44];       // [t][u] pitch 44: b128 write+read
    __shared__ float range_l[2];

    int tid = threadIdx.x;
    int b = blockIdx.y;
    int t0 = blockIdx.x * TT;
    long r0 = (long)b * TD + t0;

    // ---- stage params: 1024 floats = 256 float4
    if (tid < 256) {
        float4 v = *(const float4*)(ep + r0 * PP + tid * 4);
        int tt_ = tid >> 3, j = (tid & 7) * 4;
        *(float4*)&params_l[tt_ * 36 + j] = v;
    }
    __syncthreads();

    // ---- phi role: thread owns t = tt (tid&31), u-slice sub (tid>>5, 0..9)
    int tt = tid & 31;
    int sub = tid >> 5;
    float pa[KG], pnb[KG], pk[KG];
    #pragma unroll
    for (int q = 0; q < KG; q++) {
        pa[q]  = params_l[tt * 36 + q];
        pnb[q] = params_l[tt * 36 + 10 + q];
        pk[q]  = params_l[tt * 36 + 20 + q];
    }

    // ---- dynamic contributing u-range; wave 0 reduces (covers all 32 t's)
    {
        float lo = 1e30f, hi = -1e30f;
        #pragma unroll
        for (int q = 0; q < KG; q++) {
            float bits = 46.f + fmaxf(0.f, __log2f(pa[q]));
            float w = __fsqrt_rn(bits / (-pnb[q]));   // pnb<0 strictly
            lo = fminf(lo, pk[q] - w);
            hi = fmaxf(hi, pk[q] + w);
        }
        if (tid < 64) {
            #pragma unroll
            for (int mk = 1; mk < 64; mk <<= 1) {
                lo = fminf(lo, __shfl_xor(lo, mk));
                hi = fmaxf(hi, __shfl_xor(hi, mk));
            }
            if (tid == 0) { range_l[0] = lo; range_l[1] = hi; }
        }
    }
    __syncthreads();
    float lo_m = fminf(fmaxf(range_l[0], 0.f), (float)(UD - 1));
    float hi_m = fminf(fmaxf(range_l[1], 0.f), (float)(UD - 1));
    int ch_lo = (int)lo_m / UC;
    int ch_hi = (int)hi_m / UC;
    if (ch_lo > ch_hi) ch_lo = ch_hi;

    // ---- einsum role: thread owns t-pair ty*2, a-quad tx*4
    int tx = tid % 20;   // 0..19
    int ty = tid / 20;   // 0..15
    float4 acc0 = {0.f, 0.f, 0.f, 0.f};
    float4 acc1 = {0.f, 0.f, 0.f, 0.f};

    const float* csb = cs + (long)b * UD * AD;

    for (int ch = ch_lo; ch <= ch_hi; ch++) {
        int u0 = ch * UC;
        __syncthreads();   // protect cs_l/phi2 from previous einsum readers

        // stage char_seq chunk: 3200 floats = 800 float4, coalesced
        for (int idx = tid; idx < (UC * AD) / 4; idx += NTHR) {
            *(float4*)&cs_l[idx * 4] = *(const float4*)&csb[u0 * AD + idx * 4];
        }

        // compute phi for my t, my 4 u's; one b128 LDS write
        float ph[4];
        #pragma unroll
        for (int i = 0; i < 4; i++) {
            float uf = (float)(u0 + sub * 4 + i);
            float ss = 0.f;
            #pragma unroll
            for (int q = 0; q < KG; q++) {
                float d = uf - pk[q];
                ss += pa[q] * EXP2F(pnb[q] * d * d);
            }
            ph[i] = ss;
        }
        *(float4*)&phi2[tt * 44 + sub * 4] = make_float4(ph[0], ph[1], ph[2], ph[3]);
        __syncthreads();

        // einsum: out[t][a] += phi[t][u] * cs[u][a]; b128 phi + b128 cs
        #pragma unroll 2
        for (int g = 0; g < 10; g++) {
            float4 p0 = *(const float4*)&phi2[(ty * 2) * 44 + g * 4];
            float4 p1 = *(const float4*)&phi2[(ty * 2 + 1) * 44 + g * 4];
            #pragma unroll
            for (int i = 0; i < 4; i++) {
                float4 c4 = *(const float4*)&cs_l[(g * 4 + i) * AD + tx * 4];
                float pi0 = (i == 0) ? p0.x : (i == 1) ? p0.y : (i == 2) ? p0.z : p0.w;
                float pi1 = (i == 0) ? p1.x : (i == 1) ? p1.y : (i == 2) ? p1.z : p1.w;
                acc0.x += pi0 * c4.x; acc0.y += pi0 * c4.y;
                acc0.z += pi0 * c4.z; acc0.w += pi0 * c4.w;
                acc1.x += pi1 * c4.x; acc1.y += pi1 * c4.y;
                acc1.z += pi1 * c4.z; acc1.w += pi1 * c4.w;
            }
        }
    }

    // ---- store 2 t-rows x 4 a's
    long t = r0 + ty * 2;
    *(float4*)(out + t * AD + tx * 4) = acc0;
    *(float4*)(out + (t + 1) * AD + tx * 4) = acc1;
}

extern "C" void kernel_launch(void* const* d_in, const int* in_sizes, int n_in,
                              void* d_out, int out_size, void* d_ws, size_t ws_size,
                              hipStream_t stream) {
    const float* lstm = (const float*)d_in[0];   // [16,1024,512]
    const float* cs   = (const float*)d_in[1];   // [16,600,80]
    const float* W    = (const float*)d_in[2];   // [512,30]
    const float* bias = (const float*)d_in[3];   // [30]
    float* out = (float*)d_out;                  // [16,1024,80]

    float* ep = (float*)d_ws;                              // 2 MB
    unsigned short* Wfh = (unsigned short*)((char*)d_ws + (16384L * PP * 4));
    unsigned short* Wfl = Wfh + 32768;

    k_wprep<<<32, 256, 0, stream>>>(W, Wfh, Wfl);
    k_params<<<(BB * TD) / 16, 256, 0, stream>>>(lstm, Wfh, Wfl, bias, ep);
    dim3 grid(TD / TT, BB);
    k_main<<<grid, NTHR, 0, stream>>>(ep, cs, out);
}

// Round 7
// 89.102 us; speedup vs baseline: 1.4338x; 1.0437x over previous
//
#include <hip/hip_runtime.h>
#include <math.h>

#define BB 16
#define TD 1024
#define HD 512
#define UD 600
#define AD 80
#define KG 10
#define PC 30      // 3*K
#define PP 32      // padded param cols

#define LOG2E 1.4426950408889634f

#if __has_builtin(__builtin_amdgcn_exp2f)
#define EXP2F(x) __builtin_amdgcn_exp2f(x)
#else
#define EXP2F(x) exp2f(x)
#endif

typedef short v8s __attribute__((ext_vector_type(8)));
typedef float v4f __attribute__((ext_vector_type(4)));

__device__ inline unsigned short f2bf(float f) {            // RNE fp32->bf16
    unsigned u = __float_as_uint(f);
    return (unsigned short)((u + 0x7FFF + ((u >> 16) & 1)) >> 16);
}

// ======== kernel 0: pack W into MFMA B-fragment order, split bf16 hi/lo ====
// mfma_f32_16x16x32_bf16 B-layout: B[k = (lane>>4)*8 + j][n = lane&15].
// Wf[((kt*2+n)*64 + lane)*8 + j] covers k = kt*32 + (lane>>4)*8 + j,
// c = n*16 + (lane&15)  (c>=30 zero-padded). 32768 entries each for hi/lo.
__global__ void k_wprep(const float* __restrict__ W,
                        unsigned short* __restrict__ Wfh,
                        unsigned short* __restrict__ Wfl) {
    int p = blockIdx.x * 256 + threadIdx.x;
    for (; p < 32768; p += 256 * 32) {
        int j = p & 7, l = (p >> 3) & 63, n = (p >> 9) & 1, kt = p >> 10;
        int k = kt * 32 + ((l >> 4) * 8) + j;
        int c = n * 16 + (l & 15);
        float v = (c < PC) ? W[k * PC + c] : 0.f;
        unsigned short h = f2bf(v);
        float hi_f = __uint_as_float(((unsigned)h) << 16);
        Wfh[p] = h;
        Wfl[p] = f2bf(v - hi_f);
    }
}

// ======== fused kernel: params GEMM (MFMA split-bf16) + exp + gaussian =====
// ======== window + btu,bua->bta einsum, all per-block self-sufficient =====
// 512 blocks x 320 thr (5 waves); block = (batch b, 32 t's).
// Phase A: waves 0-3 compute the 32x512 @ 512x32 params GEMM; wave wv owns
//   k in [128wv, 128wv+128) = 4 ktiles; 2 Mtiles x 2 Ntiles; 3 MFMA passes
//   (hh, lh, hl) ~= fp32 accuracy (R5-verified path, absmax unchanged).
// Phase B: 4 partials reduced in LDS + exp transform -> params_l (no global
//   ep round-trip; fusion also removes 2 launch boundaries).
// Phase C: dynamic u-range (skip chunks where every term < 2^-46*max(a,1);
//   abs err < 1e-9 for ANY input, graceful full-loop fallback) + einsum.
#define TT 32     // t-tile per block
#define UC 40     // u chunk
#define NCHUNK 15 // 600/40
#define NTHR 320  // 5 waves

__global__ __launch_bounds__(NTHR) void k_fused(const float* __restrict__ x,
                                                const unsigned short* __restrict__ Wfh,
                                                const unsigned short* __restrict__ Wfl,
                                                const float* __restrict__ bias,
                                                const float* __restrict__ cs,
                                                float* __restrict__ out) {
    __shared__ float red[4 * TT * 33];    // [wv][row32][col33] 16896 B
    __shared__ float params_l[TT * 36];   // pitch 36
    __shared__ float cs_l[UC * AD];       // [u][a] pitch 80
    __shared__ float phi2[TT * 44];       // [t][u] pitch 44: b128 write+read
    __shared__ float range_l[2];

    int tid = threadIdx.x;
    int b = blockIdx.y;
    int t0 = blockIdx.x * TT;
    long r0 = (long)b * TD + t0;          // first global row of this tile

    int wv = tid >> 6;                    // 0..4
    int l = tid & 63;
    int quad = l >> 4, m = l & 15;

    // ================= Phase A: params GEMM (waves 0-3) =================
    if (wv < 4) {
        v4f acc[2][2];
        #pragma unroll
        for (int mt = 0; mt < 2; mt++)
            #pragma unroll
            for (int n = 0; n < 2; n++)
                acc[mt][n] = (v4f){0.f, 0.f, 0.f, 0.f};

        #pragma unroll
        for (int kt = 0; kt < 4; kt++) {
            int g = wv * 4 + kt;          // global ktile 0..15
            v8s ah[2], al[2];
            #pragma unroll
            for (int mt = 0; mt < 2; mt++) {
                const float* xr = x + (r0 + mt * 16 + m) * HD + g * 32 + quad * 8;
                float4 xa = *(const float4*)(xr);
                float4 xb = *(const float4*)(xr + 4);
                float xf[8] = {xa.x, xa.y, xa.z, xa.w, xb.x, xb.y, xb.z, xb.w};
                #pragma unroll
                for (int j = 0; j < 8; j++) {
                    unsigned short h = f2bf(xf[j]);
                    ah[mt][j] = (short)h;
                    al[mt][j] = (short)f2bf(xf[j] - __uint_as_float(((unsigned)h) << 16));
                }
            }
            #pragma unroll
            for (int n = 0; n < 2; n++) {
                uint4 uh = *(const uint4*)&Wfh[((g * 2 + n) * 64 + l) * 8];
                uint4 ul = *(const uint4*)&Wfl[((g * 2 + n) * 64 + l) * 8];
                v8s bh, bl;
                __builtin_memcpy(&bh, &uh, 16);
                __builtin_memcpy(&bl, &ul, 16);
                #pragma unroll
                for (int mt = 0; mt < 2; mt++) {
                    acc[mt][n] = __builtin_amdgcn_mfma_f32_16x16x32_bf16(ah[mt], bh, acc[mt][n], 0, 0, 0);
                    acc[mt][n] = __builtin_amdgcn_mfma_f32_16x16x32_bf16(al[mt], bh, acc[mt][n], 0, 0, 0);
                    acc[mt][n] = __builtin_amdgcn_mfma_f32_16x16x32_bf16(ah[mt], bl, acc[mt][n], 0, 0, 0);
                }
            }
        }

        // C/D layout: row = quad*4 + reg (+ mt*16), col = lane&15 (+ n*16)
        #pragma unroll
        for (int mt = 0; mt < 2; mt++)
            #pragma unroll
            for (int n = 0; n < 2; n++)
                #pragma unroll
                for (int r = 0; r < 4; r++)
                    red[wv * (TT * 33) + (mt * 16 + quad * 4 + r) * 33 + n * 16 + m]
                        = acc[mt][n][r];
    }
    __syncthreads();

    // ================= Phase B: reduce + exp transform ==================
    // params_l[t][c]: c 0..9 a=exp(p); 10..19 nb=-exp(p)*log2e; 20..29 k=exp(p)
    for (int idx = tid; idx < TT * PC; idx += NTHR) {
        int r = idx / PC, c = idx - r * PC;
        float s = red[0 * (TT * 33) + r * 33 + c] + red[1 * (TT * 33) + r * 33 + c]
                + red[2 * (TT * 33) + r * 33 + c] + red[3 * (TT * 33) + r * 33 + c];
        float e = __expf(s + bias[c]);
        params_l[r * 36 + c] = (c >= 10 && c < 20) ? (-e * LOG2E) : e;
    }
    __syncthreads();

    // ================= Phase C: gaussian window + einsum ================
    int tt = tid & 31;
    int sub = tid >> 5;                   // 0..9
    float pa[KG], pnb[KG], pk[KG];
    #pragma unroll
    for (int q = 0; q < KG; q++) {
        pa[q]  = params_l[tt * 36 + q];
        pnb[q] = params_l[tt * 36 + 10 + q];
        pk[q]  = params_l[tt * 36 + 20 + q];
    }

    // dynamic contributing u-range; wave 0 reduces (its 64 lanes cover all t)
    {
        float lo = 1e30f, hi = -1e30f;
        #pragma unroll
        for (int q = 0; q < KG; q++) {
            float bits = 46.f + fmaxf(0.f, __log2f(pa[q]));
            float w = __fsqrt_rn(bits / (-pnb[q]));   // pnb<0 strictly
            lo = fminf(lo, pk[q] - w);
            hi = fmaxf(hi, pk[q] + w);
        }
        if (tid < 64) {
            #pragma unroll
            for (int mk = 1; mk < 64; mk <<= 1) {
                lo = fminf(lo, __shfl_xor(lo, mk));
                hi = fmaxf(hi, __shfl_xor(hi, mk));
            }
            if (tid == 0) { range_l[0] = lo; range_l[1] = hi; }
        }
    }
    __syncthreads();
    float lo_m = fminf(fmaxf(range_l[0], 0.f), (float)(UD - 1));
    float hi_m = fminf(fmaxf(range_l[1], 0.f), (float)(UD - 1));
    int ch_lo = (int)lo_m / UC;
    int ch_hi = (int)hi_m / UC;
    if (ch_lo > ch_hi) ch_lo = ch_hi;

    // einsum role: thread owns t-pair ty*2, a-quad tx*4
    int tx = tid % 20;   // 0..19
    int ty = tid / 20;   // 0..15
    float4 acc0 = {0.f, 0.f, 0.f, 0.f};
    float4 acc1 = {0.f, 0.f, 0.f, 0.f};

    const float* csb = cs + (long)b * UD * AD;

    for (int ch = ch_lo; ch <= ch_hi; ch++) {
        int u0 = ch * UC;
        __syncthreads();   // protect cs_l/phi2 from previous chunk's readers

        // stage char_seq chunk: 3200 floats = 800 float4, coalesced
        for (int idx = tid; idx < (UC * AD) / 4; idx += NTHR) {
            *(float4*)&cs_l[idx * 4] = *(const float4*)&csb[u0 * AD + idx * 4];
        }

        // compute phi for my t, my 4 u's; one b128 LDS write
        float ph[4];
        #pragma unroll
        for (int i = 0; i < 4; i++) {
            float uf = (float)(u0 + sub * 4 + i);
            float ss = 0.f;
            #pragma unroll
            for (int q = 0; q < KG; q++) {
                float d = uf - pk[q];
                ss += pa[q] * EXP2F(pnb[q] * d * d);
            }
            ph[i] = ss;
        }
        *(float4*)&phi2[tt * 44 + sub * 4] = make_float4(ph[0], ph[1], ph[2], ph[3]);
        __syncthreads();

        // einsum: out[t][a] += phi[t][u] * cs[u][a]; b128 phi + b128 cs
        #pragma unroll 2
        for (int g = 0; g < 10; g++) {
            float4 p0 = *(const float4*)&phi2[(ty * 2) * 44 + g * 4];
            float4 p1 = *(const float4*)&phi2[(ty * 2 + 1) * 44 + g * 4];
            #pragma unroll
            for (int i = 0; i < 4; i++) {
                float4 c4 = *(const float4*)&cs_l[(g * 4 + i) * AD + tx * 4];
                float pi0 = (i == 0) ? p0.x : (i == 1) ? p0.y : (i == 2) ? p0.z : p0.w;
                float pi1 = (i == 0) ? p1.x : (i == 1) ? p1.y : (i == 2) ? p1.z : p1.w;
                acc0.x += pi0 * c4.x; acc0.y += pi0 * c4.y;
                acc0.z += pi0 * c4.z; acc0.w += pi0 * c4.w;
                acc1.x += pi1 * c4.x; acc1.y += pi1 * c4.y;
                acc1.z += pi1 * c4.z; acc1.w += pi1 * c4.w;
            }
        }
    }

    // store 2 t-rows x 4 a's
    long t = r0 + ty * 2;
    *(float4*)(out + t * AD + tx * 4) = acc0;
    *(float4*)(out + (t + 1) * AD + tx * 4) = acc1;
}

extern "C" void kernel_launch(void* const* d_in, const int* in_sizes, int n_in,
                              void* d_out, int out_size, void* d_ws, size_t ws_size,
                              hipStream_t stream) {
    const float* lstm = (const float*)d_in[0];   // [16,1024,512]
    const float* cs   = (const float*)d_in[1];   // [16,600,80]
    const float* W    = (const float*)d_in[2];   // [512,30]
    const float* bias = (const float*)d_in[3];   // [30]
    float* out = (float*)d_out;                  // [16,1024,80]

    unsigned short* Wfh = (unsigned short*)d_ws;     // 64 KB
    unsigned short* Wfl = Wfh + 32768;               // 64 KB

    k_wprep<<<32, 256, 0, stream>>>(W, Wfh, Wfl);
    dim3 grid(TD / TT, BB);
    k_fused<<<grid, NTHR, 0, stream>>>(lstm, Wfh, Wfl, bias, cs, out);
}